// Round 10
// baseline (2525.020 us; speedup 1.0000x reference)
//
#include <hip/hip_runtime.h>

namespace {
constexpr int NN = 100000;
constexpr int NE = 600000;
constexpr int H  = 128;

__global__ __launch_bounds__(256) void write_marker(float* __restrict__ out,
                                                    int n, float val) {
  int i = blockIdx.x * 256 + threadIdx.x;
  if (i < n) out[i] = val;
}

__global__ __launch_bounds__(256) void zero_f4(float4* __restrict__ p, int n4) {
  int i = blockIdx.x * 256 + threadIdx.x;
  if (i < n4) p[i] = float4{0.f, 0.f, 0.f, 0.f};
}

// agg[dst[e]][c..c+3] += embed[node_id[src[e]]][c..c+3] * norm[src[e]]
__global__ __launch_bounds__(256) void scatter_l1(
    const int* __restrict__ src, const int* __restrict__ dst,
    const int* __restrict__ node_id, const float* __restrict__ embed,
    const float* __restrict__ norm, float* __restrict__ agg) {
  int idx = blockIdx.x * 256 + threadIdx.x;  // [0, NE*32)
  int e = idx >> 5;
  if (e >= NE) return;
  int c = (idx & 31) << 2;                   // 4 columns per thread
  int s = src[e];
  float nrm = norm[s];
  const float4 v = *reinterpret_cast<const float4*>(embed + (size_t)node_id[s] * H + c);
  float* o = agg + (size_t)dst[e] * H + c;
  atomicAdd(o + 0, v.x * nrm);
  atomicAdd(o + 1, v.y * nrm);
  atomicAdd(o + 2, v.z * nrm);
  atomicAdd(o + 3, v.w * nrm);
}

// agg[dst[e]][c..c+3] += h1[src[e]][c..c+3] * norm[src[e]]   (h1 fp32, in d_out)
__global__ __launch_bounds__(256) void scatter_l2(
    const int* __restrict__ src, const int* __restrict__ dst,
    const float* __restrict__ h1, const float* __restrict__ norm,
    float* __restrict__ agg) {
  int idx = blockIdx.x * 256 + threadIdx.x;
  int e = idx >> 5;
  if (e >= NE) return;
  int c = (idx & 31) << 2;
  int s = src[e];
  float nrm = norm[s];
  const float4 v = *reinterpret_cast<const float4*>(h1 + (size_t)s * H + c);
  float* o = agg + (size_t)dst[e] * H + c;
  atomicAdd(o + 0, v.x * nrm);
  atomicAdd(o + 1, v.y * nrm);
  atomicAdd(o + 2, v.z * nrm);
  atomicAdd(o + 3, v.w * nrm);
}

// out[row][j] = LReLU( (sum_k agg[row][k]*W[k][j]) * norm[row] + b[j] )   fp32 store
__global__ __launch_bounds__(128) void row_gemm_act(
    const float* __restrict__ agg, const float* __restrict__ W,
    const float* __restrict__ norm, const float* __restrict__ bias,
    float* __restrict__ out) {
  __shared__ float hs[H];
  const int row = blockIdx.x, j = threadIdx.x;
  hs[j] = agg[(size_t)row * H + j];
  __syncthreads();
  float acc = 0.f;
#pragma unroll
  for (int k = 0; k < H; ++k) acc += hs[k] * W[k * H + j];
  float v = acc * norm[row] + bias[j];
  v = v > 0.f ? v : 0.2f * v;
  out[(size_t)row * H + j] = v;
}
}  // namespace

extern "C" void kernel_launch(void* const* d_in, const int* in_sizes, int n_in,
                              void* d_out, int out_size, void* d_ws, size_t ws_size,
                              hipStream_t stream) {
  float* out = (float*)d_out;                 // OUTPUT IS FP32 (reference returns float32)
  const int nElem = NN * H;                   // 12.8M
  const int mkBl  = (out_size + 255) / 256;

  bool order_ok =
      (n_in == 9 && in_sizes[0] == NN && in_sizes[1] == NE && in_sizes[2] == NE &&
       in_sizes[3] == NN && in_sizes[4] == NN * H && in_sizes[5] == H * H &&
       in_sizes[6] == H && in_sizes[7] == H * H && in_sizes[8] == H);
  if (!order_ok || out_size != nElem) {
    write_marker<<<mkBl, 256, 0, stream>>>(out, out_size,
                                           (out_size != nElem) ? 300.0f : 200.0f);
    return;
  }
  if (ws_size < (size_t)nElem * 4) {
    write_marker<<<mkBl, 256, 0, stream>>>(out, out_size,
                                           2.0f + (float)(ws_size >> 20));
    return;
  }

  const int* node_id = (const int*)d_in[0];
  const int* src     = (const int*)d_in[1];   // gather side (reference direction)
  const int* dst     = (const int*)d_in[2];   // scatter side
  const float* norm  = (const float*)d_in[3];
  const float* embed = (const float*)d_in[4];
  const float* W1    = (const float*)d_in[5];
  const float* b1    = (const float*)d_in[6];
  const float* W2    = (const float*)d_in[7];
  const float* b2    = (const float*)d_in[8];

  float* agg = (float*)d_ws;                  // fp32 [NN,H] = 51.2 MB (fits confirmed ws)
  float* h1  = out;                           // d_out holds fp32 h1 between layers

  const int zeroBl = (nElem / 4 + 255) / 256;
  const int scatBl = (NE * 32 + 255) / 256;

  // ---- layer 1 ----
  zero_f4<<<zeroBl, 256, 0, stream>>>((float4*)agg, nElem / 4);
  scatter_l1<<<scatBl, 256, 0, stream>>>(src, dst, node_id, embed, norm, agg);
  row_gemm_act<<<NN, 128, 0, stream>>>(agg, W1, norm, b1, h1);

  // ---- layer 2 ----
  zero_f4<<<zeroBl, 256, 0, stream>>>((float4*)agg, nElem / 4);
  scatter_l2<<<scatBl, 256, 0, stream>>>(src, dst, h1, norm, agg);
  row_gemm_act<<<NN, 128, 0, stream>>>(agg, W2, norm, b2, out);
}